// Round 4
// baseline (17.457 us; speedup 1.0000x reference)
//
#include <hip/hip_runtime.h>

#define BB 4096
#define SS 256
#define NOPS 7

typedef float f32x4 __attribute__((ext_vector_type(4)));

__global__ __launch_bounds__(256) void arth_kernel(
    const float* __restrict__ tv_in,
    const float* __restrict__ td_in,
    const float* __restrict__ op_in,
    const float* __restrict__ if_fin,
    const float* __restrict__ if_val,
    const int* __restrict__ start_pos_p,
    float* __restrict__ out_tv,
    float* __restrict__ out_td,
    float* __restrict__ out_op,
    float* __restrict__ out_iff,
    float* __restrict__ out_iv)
{
    __shared__ float s_op[SS * NOPS];
    __shared__ float s_td[SS];
    __shared__ unsigned char s_amax[SS];
    __shared__ unsigned long long sm_op[4];
    __shared__ unsigned long long sm_num[4];

    const int b = blockIdx.x;
    const int t = threadIdx.x;
    const size_t rbase = (size_t)b * SS;
    const size_t obase = (size_t)b * (SS * NOPS);

    // Block-uniform scalars: s_load, overlapped with the vector loads below.
    const int start_pos = *start_pos_p;
    const float fin_f = if_fin[b];
    const float iv0 = if_val[b];

    const f32x4* in4 = (const f32x4*)(op_in + obase);
    f32x4* o4 = (f32x4*)(out_op + obase);
    f32x4* s4 = (f32x4*)s_op;

    // ---- Phase 1: issue ALL global loads back-to-back (MLP). ----
    f32x4 v0 = in4[t];
    f32x4 v1;
    if (t < 192) v1 = in4[256 + t];
    const float tvv = tv_in[rbase + t];
    const float tdv = td_in[rbase + t];

    // ---- Phase 2: plain cached stores — working set (74.5 MB) fits L3;
    // let Infinity Cache retain it across graph replays (nt defeated this).
    o4[t] = v0;
    s4[t] = v0;
    if (t < 192) {
        o4[256 + t] = v1;
        s4[256 + t] = v1;
    }
    s_td[t] = tdv;
    __syncthreads();

    // Per-position argmax over 7 ops (first-max-lowest-index = jnp.argmax).
    int am = 0;
    float best = s_op[t * NOPS];
    #pragma unroll
    for (int k = 1; k < NOPS; ++k) {
        float v = s_op[t * NOPS + k];
        if (v > best) { best = v; am = k; }
    }
    s_amax[t] = (unsigned char)am;

    const bool validtok = (t >= start_pos) && (tvv > 0.5f);
    const bool is_num = validtok && (am == 0);
    const bool is_op = validtok && (am != 0);

    unsigned long long mo = __ballot(is_op);
    unsigned long long mn = __ballot(is_num);
    if ((t & 63) == 0) {
        sm_op[t >> 6] = mo;
        sm_num[t >> 6] = mn;
    }
    __syncthreads();

    // All threads scan the 8 mask words (wave-uniform, broadcast LDS reads).
    unsigned long long w_op0 = sm_op[0], w_op1 = sm_op[1], w_op2 = sm_op[2], w_op3 = sm_op[3];
    unsigned long long w_nm[4] = { sm_num[0], sm_num[1], sm_num[2], sm_num[3] };

    // First valid op token j (or -1).
    int j = -1;
    if (w_op0)      j = __builtin_ctzll(w_op0);
    else if (w_op1) j = 64 + __builtin_ctzll(w_op1);
    else if (w_op2) j = 128 + __builtin_ctzll(w_op2);
    else if (w_op3) j = 192 + __builtin_ctzll(w_op3);

    // Top-two push indices strictly below j (or below S if no op).
    int i0 = -1, i1 = -1;
    #pragma unroll
    for (int ww = 3; ww >= 0; --ww) {
        if (i1 >= 0) continue;
        unsigned long long m = w_nm[ww];
        if (j >= 0) {
            int jw = j - ww * 64;
            if (jw <= 0) m = 0ull;
            else if (jw < 64) m &= ((1ull << jw) - 1ull);
        }
        while (m && i1 < 0) {
            int bit = 63 - __builtin_clzll(m);
            if (i0 < 0) i0 = ww * 64 + bit;
            else        i1 = ww * 64 + bit;
            m &= ~(1ull << bit);
        }
    }

    const bool finished = fin_f > 0.5f;
    const bool valid0 = iv0 > 0.5f;

    float otv = tvv, otd = tdv;
    float iff, ivout;
    if (finished) {
        iff = 1.0f;
        ivout = iv0;
    } else if (!valid0) {
        iff = 0.0f;
        ivout = 0.0f;
    } else if (j < 0) {
        ivout = 1.0f;
        iff = (i0 >= 0 && i1 < 0) ? 1.0f : 0.0f;
    } else if (i1 >= 0) {
        float h0 = s_td[i0];   // broadcast read
        float h1 = s_td[i1];   // broadcast read
        int op = s_amax[j];    // broadcast read
        float res;
        switch (op) {
            case 2: res = h1 + h0; break;
            case 3: res = h1 - h0; break;
            case 4: res = h1 * h0; break;
            case 5: res = h1 / (h0 + 1e-7f); break;
            case 6: res = powf(fmaxf(h1, 1e-7f), h0); break;
            default: res = 0.0f; break;   // op index 1 -> zero
        }
        if (t == i0) otd = res;
        if (t == i1 || t == j) otv = 0.0f;
        ivout = 1.0f;
        iff = 0.0f;
    } else {
        ivout = 0.0f;
        iff = 0.0f;
    }

    // Plain cached writeback.
    out_tv[rbase + t] = otv;
    out_td[rbase + t] = otd;
    if (t == 0) {
        out_iff[b] = iff;
        out_iv[b] = ivout;
    }
}

extern "C" void kernel_launch(void* const* d_in, const int* in_sizes, int n_in,
                              void* d_out, int out_size, void* d_ws, size_t ws_size,
                              hipStream_t stream) {
    const float* tv_in = (const float*)d_in[0];   // trans_valid (B,S)
    const float* td_in = (const float*)d_in[1];   // trans_dense (B,S)
    const float* op_in = (const float*)d_in[2];   // trans_op (B,S,7)
    const float* if_fin = (const float*)d_in[3];  // if_finished (B,)
    const float* if_val = (const float*)d_in[4];  // if_valid (B,)
    const int* start_pos = (const int*)d_in[5];   // scalar

    float* out = (float*)d_out;
    float* out_tv = out;                                    // B*S
    float* out_td = out + (size_t)BB * SS;                  // B*S
    float* out_op = out + (size_t)2 * BB * SS;              // B*S*7
    float* out_iff = out + (size_t)9 * BB * SS;             // B
    float* out_iv = out + (size_t)9 * BB * SS + BB;         // B

    arth_kernel<<<BB, SS, 0, stream>>>(tv_in, td_in, op_in, if_fin, if_val,
                                       start_pos, out_tv, out_td, out_op,
                                       out_iff, out_iv);
}

// Round 5
// 16.602 us; speedup vs baseline: 1.0515x; 1.0515x over previous
//
#include <hip/hip_runtime.h>

#define BB 4096
#define SS 256
#define NOPS 7

typedef float f32x4 __attribute__((ext_vector_type(4)));

__global__ __launch_bounds__(256) void arth_kernel(
    const float* __restrict__ tv_in,
    const float* __restrict__ td_in,
    const float* __restrict__ op_in,
    const float* __restrict__ if_fin,
    const float* __restrict__ if_val,
    const int* __restrict__ start_pos_p,
    float* __restrict__ out_tv,
    float* __restrict__ out_td,
    float* __restrict__ out_op,
    float* __restrict__ out_iff,
    float* __restrict__ out_iv)
{
    // Tiny LDS only: 1.3 KB/block (was 8.5 KB). Argmax no longer staged.
    __shared__ float s_td[SS];
    __shared__ unsigned char s_amax[SS];
    __shared__ unsigned long long sm_op[4];
    __shared__ unsigned long long sm_num[4];

    const int b = blockIdx.x;
    const int t = threadIdx.x;
    const size_t rbase = (size_t)b * SS;
    const size_t obase = (size_t)b * (SS * NOPS);

    // Block-uniform scalars (s_load, overlapped with everything below).
    const int start_pos = *start_pos_p;
    const float fin_f = if_fin[b];
    const float iv0 = if_val[b];

    const f32x4* in4 = (const f32x4*)(op_in + obase);
    f32x4* o4 = (f32x4*)(out_op + obase);

    // ---- Issue ALL global loads back-to-back. ----
    // Copy path: 448 float4 per row.
    f32x4 v0 = in4[t];
    f32x4 v1;
    if (t < 192) v1 = in4[256 + t];
    // Argmax path: thread t's 7 contiguous floats. Same 1792B wave window as
    // the copy loads -> lines are L1-hot, no extra HBM traffic.
    const float* p = op_in + obase + (size_t)t * NOPS;
    const float a0 = p[0], a1 = p[1], a2 = p[2], a3 = p[3];
    const float a4 = p[4], a5 = p[5], a6 = p[6];
    const float tvv = tv_in[rbase + t];
    const float tdv = td_in[rbase + t];

    // Per-position argmax in registers (first-max-lowest-index = jnp.argmax).
    int am = 0; float best = a0;
    if (a1 > best) { best = a1; am = 1; }
    if (a2 > best) { best = a2; am = 2; }
    if (a3 > best) { best = a3; am = 3; }
    if (a4 > best) { best = a4; am = 4; }
    if (a5 > best) { best = a5; am = 5; }
    if (a6 > best) { best = a6; am = 6; }

    s_td[t] = tdv;
    s_amax[t] = (unsigned char)am;

    const bool validtok = (t >= start_pos) && (tvv > 0.5f);
    const bool is_num = validtok && (am == 0);
    const bool is_op = validtok && (am != 0);

    unsigned long long mo = __ballot(is_op);
    unsigned long long mn = __ballot(is_num);
    if ((t & 63) == 0) {
        sm_op[t >> 6] = mo;
        sm_num[t >> 6] = mn;
    }

    // Streaming copy stores: independent of the logic path, issued before the
    // barrier; nontemporal (R3 A/B showed nt stores worth ~0.7us here).
    __builtin_nontemporal_store(v0, &o4[t]);
    if (t < 192) __builtin_nontemporal_store(v1, &o4[256 + t]);

    __syncthreads();   // the ONLY barrier: publishes s_td/s_amax/masks

    // All threads scan the 8 mask words (wave-uniform, broadcast LDS reads).
    unsigned long long w_op0 = sm_op[0], w_op1 = sm_op[1], w_op2 = sm_op[2], w_op3 = sm_op[3];
    unsigned long long w_nm[4] = { sm_num[0], sm_num[1], sm_num[2], sm_num[3] };

    // First valid op token j (or -1).
    int j = -1;
    if (w_op0)      j = __builtin_ctzll(w_op0);
    else if (w_op1) j = 64 + __builtin_ctzll(w_op1);
    else if (w_op2) j = 128 + __builtin_ctzll(w_op2);
    else if (w_op3) j = 192 + __builtin_ctzll(w_op3);

    // Top-two push indices strictly below j (or below S if no op).
    int i0 = -1, i1 = -1;
    #pragma unroll
    for (int ww = 3; ww >= 0; --ww) {
        if (i1 >= 0) continue;
        unsigned long long m = w_nm[ww];
        if (j >= 0) {
            int jw = j - ww * 64;
            if (jw <= 0) m = 0ull;
            else if (jw < 64) m &= ((1ull << jw) - 1ull);
        }
        while (m && i1 < 0) {
            int bit = 63 - __builtin_clzll(m);
            if (i0 < 0) i0 = ww * 64 + bit;
            else        i1 = ww * 64 + bit;
            m &= ~(1ull << bit);
        }
    }

    const bool finished = fin_f > 0.5f;
    const bool valid0 = iv0 > 0.5f;

    float otv = tvv, otd = tdv;
    float iff, ivout;
    if (finished) {
        iff = 1.0f;
        ivout = iv0;
    } else if (!valid0) {
        iff = 0.0f;
        ivout = 0.0f;
    } else if (j < 0) {
        ivout = 1.0f;
        iff = (i0 >= 0 && i1 < 0) ? 1.0f : 0.0f;
    } else if (i1 >= 0) {
        float h0 = s_td[i0];   // broadcast read
        float h1 = s_td[i1];   // broadcast read
        int op = s_amax[j];    // broadcast read
        float res;
        switch (op) {
            case 2: res = h1 + h0; break;
            case 3: res = h1 - h0; break;
            case 4: res = h1 * h0; break;
            case 5: res = h1 / (h0 + 1e-7f); break;
            case 6: res = powf(fmaxf(h1, 1e-7f), h0); break;
            default: res = 0.0f; break;   // op index 1 -> zero
        }
        if (t == i0) otd = res;
        if (t == i1 || t == j) otv = 0.0f;
        ivout = 1.0f;
        iff = 0.0f;
    } else {
        ivout = 0.0f;
        iff = 0.0f;
    }

    // Streaming writeback straight from registers.
    __builtin_nontemporal_store(otv, &out_tv[rbase + t]);
    __builtin_nontemporal_store(otd, &out_td[rbase + t]);
    if (t == 0) {
        out_iff[b] = iff;
        out_iv[b] = ivout;
    }
}

extern "C" void kernel_launch(void* const* d_in, const int* in_sizes, int n_in,
                              void* d_out, int out_size, void* d_ws, size_t ws_size,
                              hipStream_t stream) {
    const float* tv_in = (const float*)d_in[0];   // trans_valid (B,S)
    const float* td_in = (const float*)d_in[1];   // trans_dense (B,S)
    const float* op_in = (const float*)d_in[2];   // trans_op (B,S,7)
    const float* if_fin = (const float*)d_in[3];  // if_finished (B,)
    const float* if_val = (const float*)d_in[4];  // if_valid (B,)
    const int* start_pos = (const int*)d_in[5];   // scalar

    float* out = (float*)d_out;
    float* out_tv = out;                                    // B*S
    float* out_td = out + (size_t)BB * SS;                  // B*S
    float* out_op = out + (size_t)2 * BB * SS;              // B*S*7
    float* out_iff = out + (size_t)9 * BB * SS;             // B
    float* out_iv = out + (size_t)9 * BB * SS + BB;         // B

    arth_kernel<<<BB, SS, 0, stream>>>(tv_in, td_in, op_in, if_fin, if_val,
                                       start_pos, out_tv, out_td, out_op,
                                       out_iff, out_iv);
}